// Round 17
// baseline (487.788 us; speedup 1.0000x reference)
//
#include <hip/hip_runtime.h>
#include <cstdint>

typedef unsigned short u16;
typedef unsigned int u32;
typedef unsigned char u8;
typedef unsigned long long u64;
typedef __attribute__((ext_vector_type(8))) short short8;
typedef __attribute__((ext_vector_type(4))) float f32x4;

#define CAP 131072  // max compact slots at 128^3 (~105k expected active)

__device__ __forceinline__ float bf1(u16 v){ union{u32 i; float f;} c; c.i = ((u32)v) << 16; return c.f; }
__device__ __forceinline__ u16 f2bf(float f){
    union{float f; u32 i;} c; c.f = f; u32 i = c.i;
    return (u16)((i + 0x7FFFu + ((i >> 16) & 1u)) >> 16);   // RTNE
}
__device__ __forceinline__ u16 bits2bf(u32 b){ union{u32 i; float f;} c; c.i = b; return f2bf(c.f); }

constexpr int ilog2c(int n){ return n <= 1 ? 0 : 1 + ilog2c(n / 2); }

struct PAll {
    const void* w[9];
    u32 wstart[10];
    int cin[9], cout[9], mode[9];   // 0=16x16 wfrag, 1=d0 pair(16->32), 2=subm0 pair(16->16)
    const void* s[18];
};

// ---- fused phase 0+1: blocks [0,8192) = active bitmask + packed features;
// blocks [8192,..) = weight-fragment + scale prep. Flag self-derived per thread. ----
__global__ __launch_bounds__(256)
void prepact_k(PAll J, u16* __restrict__ FR, float* __restrict__ S,
               const u16* __restrict__ s0a_probe, u32* __restrict__ flag,
               const void* __restrict__ xv, u64* __restrict__ bmask,
               u32* __restrict__ bcnt, u16* __restrict__ Xp){
    int ok = 1;
    #pragma unroll
    for (int i = 0; i < 8; i += 2){
        u16 vv = s0a_probe[i];
        if (vv < 0x3F00u || vv > 0x3FC0u) ok = 0;
    }
    const u32 isbf = ok ? 1u : 0u;

    if (blockIdx.x < 8192){
        const int v = blockIdx.x * 256 + threadIdx.x;
        const size_t N = 2097152;
        u16 vals[16];
        u32 a = 0;
        if (isbf) {
            const u16* x = (const u16*)xv;
            #pragma unroll
            for (int c = 0; c < 16; ++c){
                const u16 b = x[(size_t)c * N + v];
                vals[c] = b;
                a |= (u32)b & 0x7FFFu;
            }
        } else {
            const u32* x = (const u32*)xv;
            #pragma unroll
            for (int c = 0; c < 16; ++c){
                const u32 b = x[(size_t)c * N + v];
                vals[c] = bits2bf(b);
                a |= b & 0x7FFFFFFFu;
            }
        }
        const bool act = (a != 0);
        const u64 m = __ballot(act);
        __shared__ u32 wc[4];
        const int lane = threadIdx.x & 63, wv = threadIdx.x >> 6;
        if (lane == 0) { bmask[v >> 6] = m; wc[wv] = (u32)__popcll(m); }
        __syncthreads();
        if (threadIdx.x == 0) bcnt[blockIdx.x] = wc[0] + wc[1] + wc[2] + wc[3];
        if (act){
            u32 wbase = 0;
            for (int i = 0; i < wv; ++i) wbase += wc[i];
            const u32 local = wbase + (u32)__popcll(m & ((1ull << lane) - 1ull));
            u16* dst = Xp + ((size_t)blockIdx.x * 256 + local) * 16;
            *(short8*)(dst)     = *(const short8*)(vals);
            *(short8*)(dst + 8) = *(const short8*)(vals + 8);
        }
        return;
    }

    const int gi = (int)(blockIdx.x - 8192) * 256 + threadIdx.x;
    if (gi == 0) flag[0] = isbf;

    const int wtot = (int)J.wstart[9];
    if (gi < wtot){
        int j = 0;
        while (gi >= (int)J.wstart[j + 1]) ++j;
        const int i = gi - (int)J.wstart[j];
        const void* w = J.w[j];
        const int CIN = J.cin[j], COUT = J.cout[j];
        const int jj = i & 7;
        const int lane = (i >> 3) & 63;
        int rest = i >> 9;
        int src = -1;
        if (J.mode[j] == 0){
            const int KC = CIN >> 5, NT = COUT >> 4;
            const int nt = rest % NT; rest /= NT;
            const int kc = rest % KC; const int tap = rest / KC;
            const int k = kc * 32 + (lane >> 4) * 8 + jj;
            const int co = nt * 16 + (lane & 15);
            src = (tap * CIN + k) * COUT + co;
        } else if (J.mode[j] == 1){
            const int nt = rest & 1; const int pair = rest >> 1;
            const int kg = (lane >> 4) * 8 + jj;
            const int tap = pair * 2 + (kg >> 4);
            const int ci = kg & 15;
            const int co = nt * 16 + (lane & 15);
            if (tap < 27) src = (tap * 16 + ci) * 32 + co;
        } else {
            const int pair = rest;
            const int kg = (lane >> 4) * 8 + jj;
            const int tap = pair * 2 + (kg >> 4);
            const int ci = kg & 15;
            const int co = lane & 15;
            if (tap < 27) src = (tap * 16 + ci) * 16 + co;
        }
        float v = 0.f;
        if (src >= 0) v = isbf ? bf1(((const u16*)w)[src]) : ((const float*)w)[src];
        FR[gi] = f2bf(v);
    } else {
        const int i2 = gi - wtot;
        const int len[18] = {16,16,16,16,32,32,32,32,32,32,64,64,64,64,64,64,64,64};
        const int off[18] = {0,16,32,48,64,96,128,160,192,224,256,320,384,448,512,576,640,704};
        if (i2 < 768){
            int b = 0, base = 0;
            while (i2 >= base + len[b]) { base += len[b]; ++b; }
            const int t = i2 - base;
            const float v = isbf ? bf1(((const u16*)J.s[b])[t]) : ((const float*)J.s[b])[t];
            S[off[b] + t] = v;
        }
    }
}

// ---- fused aux: block 0 = exclusive scan; blocks 1..256 = m1 from bmask ----
__global__ __launch_bounds__(1024)
void aux_k(const u32* __restrict__ bcnt, u32* __restrict__ boff, u32* __restrict__ cnt,
           const u64* __restrict__ bmask, u8* __restrict__ m1){
    if (blockIdx.x == 0){
        __shared__ u32 lds[1024];
        const int t = threadIdx.x;
        u32 loc[8]; u32 s = 0;
        #pragma unroll
        for (int i = 0; i < 8; ++i){ loc[i] = s; s += bcnt[t * 8 + i]; }
        lds[t] = s;
        __syncthreads();
        u32 v = s;
        for (int d = 1; d < 1024; d <<= 1){
            u32 o = (t >= d) ? lds[t - d] : 0;
            __syncthreads();
            v += o; lds[t] = v;
            __syncthreads();
        }
        const u32 base = v - s;
        #pragma unroll
        for (int i = 0; i < 8; ++i) boff[t * 8 + i] = base + loc[i];
        if (t == 1023) cnt[0] = v;
    } else {
        const int v = (blockIdx.x - 1) * 1024 + threadIdx.x;
        const int xo = v & 63, yo = (v >> 6) & 63, zo = v >> 12;
        u32 a = 0;
        #pragma unroll
        for (int kz = 0; kz < 3; ++kz){ const int iz = 2*zo + kz - 1; if ((unsigned)iz >= 128u) continue;
          #pragma unroll
          for (int ky = 0; ky < 3; ++ky){ const int iy = 2*yo + ky - 1; if ((unsigned)iy >= 128u) continue;
            #pragma unroll
            for (int kx = 0; kx < 3; ++kx){ const int ix = 2*xo + kx - 1; if ((unsigned)ix >= 128u) continue;
              const int vv = (iz * 128 + iy) * 128 + ix;
              a |= (u32)((bmask[vv >> 6] >> (vv & 63)) & 1ull);
        }}}
        m1[v] = (u8)a;
    }
}

// ---- fused: scatter (Xp -> Fb0) + m1->m2 downsample ----
__global__ __launch_bounds__(256)
void scatter2m_k(const u16* __restrict__ Xp, const u64* __restrict__ bmask,
                 const u32* __restrict__ boff, int* __restrict__ idxmap,
                 int* __restrict__ alist, u16* __restrict__ f,
                 const u8* __restrict__ m1, u8* __restrict__ m2){
    if (blockIdx.x < 8192){
        const int v = blockIdx.x * 256 + threadIdx.x;
        const int lane = threadIdx.x & 63, wv = threadIdx.x >> 6;
        const u64 m = bmask[v >> 6];
        __shared__ u32 wc[4];
        if (lane == 0) wc[wv] = (u32)__popcll(m);
        __syncthreads();
        u32 wbase = 0;
        for (int i = 0; i < wv; ++i) wbase += wc[i];
        const bool act = (m >> lane) & 1ull;
        const u32 rank = (u32)__popcll(m & ((1ull << lane) - 1ull));
        int slot = -1;
        if (act){
            const u32 sl = boff[blockIdx.x] + wbase + rank;
            if (sl < CAP){
                slot = (int)sl;
                alist[slot] = v;
                const u16* src = Xp + ((size_t)blockIdx.x * 256 + wbase + rank) * 16;
                u16* dst = f + (size_t)slot * 16;
                *(short8*)(dst)     = *(const short8*)(src);
                *(short8*)(dst + 8) = *(const short8*)(src + 8);
            }
        }
        idxmap[v] = slot;
    } else {
        const int v = (int)(blockIdx.x - 8192) * 256 + threadIdx.x;
        const int xo = v & 31, yo = (v >> 5) & 31, zo = v >> 10;
        u8 a = 0;
        #pragma unroll
        for (int kz = 0; kz < 3; ++kz){ const int iz = 2*zo + kz - 1; if ((unsigned)iz >= 64u) continue;
          #pragma unroll
          for (int ky = 0; ky < 3; ++ky){ const int iy = 2*yo + ky - 1; if ((unsigned)iy >= 64u) continue;
            #pragma unroll
            for (int kx = 0; kx < 3; ++kx){ const int ix = 2*xo + kx - 1; if ((unsigned)ix >= 64u) continue;
              a |= m1[((size_t)iz * 64 + iy) * 64 + ix];
        }}}
        m2[v] = a;
    }
}

// ---- MFMA sparse subm conv at 128^3, M=32 slots per wave:
// two A-gathers share every B-load (2x gather MLP, half B-issue per MFMA).
// Per-slot accumulation order unchanged -> bit-identical. ----
__global__ __launch_bounds__(256)
void sconvm_k(const u16* __restrict__ fin, const int* __restrict__ idxmap,
              const int* __restrict__ alist, const u32* __restrict__ cnt,
              const u16* __restrict__ wf, const float* __restrict__ sc,
              const float* __restrict__ sh, u16* __restrict__ fout){
    const int n = min((int)cnt[0], CAP);
    const int j = blockIdx.x * 4 + (threadIdx.x >> 6);
    const int sbase = j * 32;
    if (sbase >= n) return;
    const int lane = threadIdx.x & 63;
    const int m = lane & 15, quad = lane >> 4;

    const int s0 = sbase + m, s1 = sbase + 16 + m;
    const int v0 = (s0 < n) ? alist[s0] : -1;
    const int v1 = (s1 < n) ? alist[s1] : -1;
    int xo0 = 0, yo0 = 0, zo0 = 0, xo1 = 0, yo1 = 0, zo1 = 0;
    if (v0 >= 0){ xo0 = v0 & 127; yo0 = (v0 >> 7) & 127; zo0 = v0 >> 14; }
    if (v1 >= 0){ xo1 = v1 & 127; yo1 = (v1 >> 7) & 127; zo1 = v1 >> 14; }

    f32x4 acc0 = {0.f,0.f,0.f,0.f}, acc1 = {0.f,0.f,0.f,0.f};
    #pragma unroll
    for (int p = 0; p < 14; ++p){
        const int tp = p * 2 + (quad >> 1);
        short8 a0 = {0,0,0,0,0,0,0,0};
        short8 a1 = {0,0,0,0,0,0,0,0};
        if (tp < 27){
            const int kz = tp / 9, ky = (tp / 3) % 3, kx = tp % 3;
            if (v0 >= 0){
                const int iz = zo0 + kz - 1, iy = yo0 + ky - 1, ix = xo0 + kx - 1;
                if ((unsigned)iz < 128u && (unsigned)iy < 128u && (unsigned)ix < 128u){
                    const int sn = idxmap[((size_t)iz * 128 + iy) * 128 + ix];
                    if (sn >= 0) a0 = *(const short8*)(fin + (size_t)sn * 16 + (quad & 1) * 8);
                }
            }
            if (v1 >= 0){
                const int iz = zo1 + kz - 1, iy = yo1 + ky - 1, ix = xo1 + kx - 1;
                if ((unsigned)iz < 128u && (unsigned)iy < 128u && (unsigned)ix < 128u){
                    const int sn = idxmap[((size_t)iz * 128 + iy) * 128 + ix];
                    if (sn >= 0) a1 = *(const short8*)(fin + (size_t)sn * 16 + (quad & 1) * 8);
                }
            }
        }
        short8 b = *(const short8*)(wf + ((size_t)p * 64 + lane) * 8);
        acc0 = __builtin_amdgcn_mfma_f32_16x16x32_bf16(a0, b, acc0, 0, 0, 0);
        acc1 = __builtin_amdgcn_mfma_f32_16x16x32_bf16(a1, b, acc1, 0, 0, 0);
    }

    const int co = lane & 15;
    const float scl = sc[co], shf = sh[co];
    #pragma unroll
    for (int r = 0; r < 4; ++r){
        const int sr0 = sbase + quad * 4 + r;
        const int sr1 = sr0 + 16;
        if (sr0 < n) fout[(size_t)sr0 * 16 + co] = f2bf(fmaxf(acc0[r] * scl + shf, 0.f));
        if (sr1 < n) fout[(size_t)sr1 * 16 + co] = f2bf(fmaxf(acc1[r] * scl + shf, 0.f));
    }
}

// ---- down0 MFMA, M=32 voxels per wave: 2 A-gathers x 2 B-loads -> 4 MFMAs ----
__global__ __launch_bounds__(256)
void convd0m_k(const u16* __restrict__ fbuf, const int* __restrict__ idxmap,
               const u16* __restrict__ wf, const float* __restrict__ sc,
               const float* __restrict__ sh, const u8* __restrict__ mk,
               u16* __restrict__ out)
{
    const int wj = blockIdx.x * 4 + (threadIdx.x >> 6);   // 8192 jobs of 32 voxels
    const int lane = threadIdx.x & 63;
    const int m = lane & 15, quad = lane >> 4;
    const int xo_b = (wj & 1) * 32;
    const int yo = (wj >> 1) & 63;
    const int zo = wj >> 7;

    f32x4 acc00 = {0.f,0.f,0.f,0.f}, acc01 = {0.f,0.f,0.f,0.f};
    f32x4 acc10 = {0.f,0.f,0.f,0.f}, acc11 = {0.f,0.f,0.f,0.f};
    const int ix_m0 = (xo_b + m) * 2 - 1;
    const int ix_m1 = ix_m0 + 32;       // voxel m+16 -> input x offset +32

    #pragma unroll
    for (int p = 0; p < 14; ++p){
        const int tp = p * 2 + (quad >> 1);
        short8 a0 = {0,0,0,0,0,0,0,0};
        short8 a1 = {0,0,0,0,0,0,0,0};
        if (tp < 27){
            const int kz = tp / 9, ky = (tp / 3) % 3, kx = tp % 3;
            const int iz = 2*zo + kz - 1, iy = 2*yo + ky - 1;
            if ((unsigned)iz < 128u && (unsigned)iy < 128u){
                const size_t rowb = ((size_t)iz * 128 + iy) * 128;
                const int ix0 = ix_m0 + kx, ix1 = ix_m1 + kx;
                if ((unsigned)ix0 < 128u){
                    const int sn = idxmap[rowb + ix0];
                    if (sn >= 0) a0 = *(const short8*)(fbuf + (size_t)sn * 16 + (quad & 1) * 8);
                }
                if ((unsigned)ix1 < 128u){
                    const int sn = idxmap[rowb + ix1];
                    if (sn >= 0) a1 = *(const short8*)(fbuf + (size_t)sn * 16 + (quad & 1) * 8);
                }
            }
        }
        short8 b0 = *(const short8*)(wf + ((size_t)(p*2+0) * 64 + lane) * 8);
        short8 b1 = *(const short8*)(wf + ((size_t)(p*2+1) * 64 + lane) * 8);
        acc00 = __builtin_amdgcn_mfma_f32_16x16x32_bf16(a0, b0, acc00, 0, 0, 0);
        acc01 = __builtin_amdgcn_mfma_f32_16x16x32_bf16(a0, b1, acc01, 0, 0, 0);
        acc10 = __builtin_amdgcn_mfma_f32_16x16x32_bf16(a1, b0, acc10, 0, 0, 0);
        acc11 = __builtin_amdgcn_mfma_f32_16x16x32_bf16(a1, b1, acc11, 0, 0, 0);
    }

    const int vb0 = wj * 32 + quad * 4;
    const int vb1 = vb0 + 16;
    const u32 m4_0 = *(const u32*)(mk + vb0);
    const u32 m4_1 = *(const u32*)(mk + vb1);
    const int n = lane & 15;
    #pragma unroll
    for (int nt = 0; nt < 2; ++nt){
        const int co = nt * 16 + n;
        const float s = sc[co], h = sh[co];
        const f32x4 accA = nt ? acc01 : acc00;
        const f32x4 accB = nt ? acc11 : acc10;
        #pragma unroll
        for (int r = 0; r < 4; ++r){
            float v0 = fmaxf(accA[r] * s + h, 0.f);
            float v1 = fmaxf(accB[r] * s + h, 0.f);
            v0 = ((m4_0 >> (8*r)) & 0xFFu) ? v0 : 0.f;
            v1 = ((m4_1 >> (8*r)) & 0xFFu) ? v1 : 0.f;
            out[(size_t)(vb0 + r) * 32 + co] = f2bf(v0);
            out[(size_t)(vb1 + r) * 32 + co] = f2bf(v1);
        }
    }
}

// ---- generic direct-global MFMA conv; retained for down1 (stride 2) only ----
template<int DIN, int DOUT, int CIN, int COUT, int STRIDE, bool FINAL>
__global__ __launch_bounds__(256)
void mconv_k(const u16* __restrict__ in, const u16* __restrict__ wf,
             const float* __restrict__ sc, const float* __restrict__ sh,
             const u8* __restrict__ mk, void* __restrict__ out,
             const u32* __restrict__ flag)
{
    constexpr int KC = CIN / 32;
    constexpr int NT = COUT / 16;
    constexpr int XT = DOUT / 16;
    const int wj = blockIdx.x * 4 + (threadIdx.x >> 6);
    const int lane = threadIdx.x & 63;
    const int m = lane & 15, quad = lane >> 4;

    const int xo_b = (wj % XT) * 16;
    const int yo = (wj / XT) % DOUT;
    const int zo = wj / (XT * DOUT);

    f32x4 acc[NT];
    #pragma unroll
    for (int i = 0; i < NT; ++i) acc[i] = (f32x4){0.f,0.f,0.f,0.f};

    const int ix0 = (xo_b + m) * STRIDE - 1;
    for (int kz = 0; kz < 3; ++kz){
      const int iz = zo * STRIDE + kz - 1;
      if ((unsigned)iz >= (unsigned)DIN) continue;
      for (int ky = 0; ky < 3; ++ky){
        const int iy = yo * STRIDE + ky - 1;
        if ((unsigned)iy >= (unsigned)DIN) continue;
        const size_t rowb = ((size_t)iz * DIN + iy) * DIN;
        #pragma unroll
        for (int kx = 0; kx < 3; ++kx){
          const int ix = ix0 + kx;
          const bool v = (unsigned)ix < (unsigned)DIN;
          const int tap = (kz*3 + ky)*3 + kx;
          const u16* ap = in + (rowb + ix) * CIN + quad * 8;
          const u16* bp = wf + (size_t)tap * KC * NT * 512 + lane * 8;
          #pragma unroll
          for (int kc = 0; kc < KC; ++kc){
            short8 a = {0,0,0,0,0,0,0,0};
            if (v) a = *(const short8*)(ap + kc * 32);
            #pragma unroll
            for (int nt = 0; nt < NT; ++nt){
              short8 b = *(const short8*)(bp + (kc * NT + nt) * 512);
              acc[nt] = __builtin_amdgcn_mfma_f32_16x16x32_bf16(a, b, acc[nt], 0, 0, 0);
            }
          }
    }}}

    const int vb = wj * 16 + quad * 4;
    const u32 m4 = *(const u32*)(mk + vb);
    const int n = lane & 15;
    #pragma unroll
    for (int nt = 0; nt < NT; ++nt){
        const int co = nt * 16 + n;
        const float s = sc[co], h = sh[co];
        #pragma unroll
        for (int r = 0; r < 4; ++r){
            float val = fmaxf(acc[nt][r] * s + h, 0.f);
            val = ((m4 >> (8*r)) & 0xFFu) ? val : 0.f;
            ((u16*)out)[(size_t)(vb + r) * COUT + co] = f2bf(val);
        }
    }
    (void)flag;
}

// ---- LDS-staged 16x16 MFMA conv, stride 1, 2x2 output rows per block, M=32/wave ----
template<int D, int CIN, int COUT, bool FINAL>
__global__ __launch_bounds__((D/32)*4*64)
void mconvw_k(const u16* __restrict__ in, const u16* __restrict__ wf,
              const float* __restrict__ sc, const float* __restrict__ sh,
              const u8* __restrict__ mk, void* __restrict__ out,
              const u32* __restrict__ flag)
{
    constexpr int KC = CIN / 32;
    constexpr int NT = COUT / 16;
    constexpr int CH8 = CIN / 8;
    constexpr int WPR = D / 32;
    constexpr int BT = WPR * 4 * 64;
    __shared__ u16 tile[16 * 2048];

    const int t = threadIdx.x;
    const int yp = blockIdx.x % (D / 2);
    const int zp = blockIdx.x / (D / 2);

    #pragma unroll
    for (int ri = 0; ri < 16; ++ri){
        const int dz = ri >> 2, jy = ri & 3;
        const int iz = 2*zp + dz - 1, iy = 2*yp + jy - 1;
        if ((unsigned)iz < (unsigned)D && (unsigned)iy < (unsigned)D){
            const u16* src = in + ((size_t)(iz * D + iy) * D) * CIN;
            u16* dst = &tile[ri * 2048];
            for (int c = t; c < D * CH8; c += BT){
                const int x = c / CH8, c8 = c % CH8;
                *(short8*)(dst + (c8 * D + x) * 8) = *(const short8*)(src + c * 8);
            }
        }
    }
    __syncthreads();

    const int lane = t & 63, w = t >> 6;
    const int r = w / WPR;
    const int r2z = r >> 1, r2y = r & 1;
    const int xo_b = (w % WPR) * 32;
    const int zo = 2*zp + r2z, yo = 2*yp + r2y;
    const int m = lane & 15, quad = lane >> 4;

    f32x4 acc0[NT], acc1[NT];
    #pragma unroll
    for (int i = 0; i < NT; ++i){ acc0[i] = (f32x4){0.f,0.f,0.f,0.f}; acc1[i] = (f32x4){0.f,0.f,0.f,0.f}; }

    #pragma unroll
    for (int kz = 0; kz < 3; ++kz){
      const int iz = zo + kz - 1;
      if ((unsigned)iz >= (unsigned)D) continue;
      #pragma unroll
      for (int ky = 0; ky < 3; ++ky){
        const int iy = yo + ky - 1;
        if ((unsigned)iy >= (unsigned)D) continue;
        const u16* row = &tile[((r2z + kz) * 4 + (r2y + ky)) * 2048];
        #pragma unroll
        for (int kx = 0; kx < 3; ++kx){
          const int ix0 = xo_b + m + kx - 1;
          const int ix1 = ix0 + 16;
          const bool aok0 = (unsigned)ix0 < (unsigned)D;
          const bool aok1 = (unsigned)ix1 < (unsigned)D;
          const int tap = (kz * 3 + ky) * 3 + kx;
          const u16* bp = wf + (size_t)tap * KC * NT * 512 + lane * 8;
          #pragma unroll
          for (int kc = 0; kc < KC; ++kc){
            short8 a0 = {0,0,0,0,0,0,0,0};
            short8 a1 = {0,0,0,0,0,0,0,0};
            if (aok0) a0 = *(const short8*)(row + ((kc * 4 + quad) * D + ix0) * 8);
            if (aok1) a1 = *(const short8*)(row + ((kc * 4 + quad) * D + ix1) * 8);
            #pragma unroll
            for (int nt = 0; nt < NT; ++nt){
              short8 b = *(const short8*)(bp + (kc * NT + nt) * 512);
              acc0[nt] = __builtin_amdgcn_mfma_f32_16x16x32_bf16(a0, b, acc0[nt], 0, 0, 0);
              acc1[nt] = __builtin_amdgcn_mfma_f32_16x16x32_bf16(a1, b, acc1[nt], 0, 0, 0);
            }
          }
        }
      }
    }

    const int base = (zo * D + yo) * D;
    const int vb0 = base + xo_b + quad * 4;
    const int vb1 = vb0 + 16;
    const u32 m4_0 = *(const u32*)(mk + vb0);
    const u32 m4_1 = *(const u32*)(mk + vb1);
    const int n = lane & 15;
    if (FINAL) {
        const bool bfout = flag[0] != 0;
        #pragma unroll
        for (int nt = 0; nt < NT; ++nt){
            const int co = nt * 16 + n;
            const float s = sc[co], h = sh[co];
            float4 o0, o1;
            float* p0 = &o0.x; float* p1 = &o1.x;
            #pragma unroll
            for (int r4 = 0; r4 < 4; ++r4){
                float v0 = fmaxf(acc0[nt][r4] * s + h, 0.f);
                float v1 = fmaxf(acc1[nt][r4] * s + h, 0.f);
                p0[r4] = ((m4_0 >> (8*r4)) & 0xFFu) ? v0 : 0.f;
                p1[r4] = ((m4_1 >> (8*r4)) & 0xFFu) ? v1 : 0.f;
            }
            if (!bfout) {
                *(float4*)((float*)out + (size_t)co * (D*D*D) + vb0) = o0;
                *(float4*)((float*)out + (size_t)co * (D*D*D) + vb1) = o1;
            } else {
                u16* ob0 = (u16*)out + (size_t)co * (D*D*D) + vb0;
                u16* ob1 = (u16*)out + (size_t)co * (D*D*D) + vb1;
                #pragma unroll
                for (int r4 = 0; r4 < 4; ++r4){ ob0[r4] = f2bf(p0[r4]); ob1[r4] = f2bf(p1[r4]); }
            }
        }
    } else {
        #pragma unroll
        for (int nt = 0; nt < NT; ++nt){
            const int co = nt * 16 + n;
            const float s = sc[co], h = sh[co];
            #pragma unroll
            for (int r4 = 0; r4 < 4; ++r4){
                float v0 = fmaxf(acc0[nt][r4] * s + h, 0.f);
                float v1 = fmaxf(acc1[nt][r4] * s + h, 0.f);
                v0 = ((m4_0 >> (8*r4)) & 0xFFu) ? v0 : 0.f;
                v1 = ((m4_1 >> (8*r4)) & 0xFFu) ? v1 : 0.f;
                ((u16*)out)[(size_t)(vb0 + r4) * COUT + co] = f2bf(v0);
                ((u16*)out)[(size_t)(vb1 + r4) * COUT + co] = f2bf(v1);
            }
        }
    }
}

extern "C" void kernel_launch(void* const* d_in, const int* in_sizes, int n_in,
                              void* d_out, int out_size, void* d_ws, size_t ws_size,
                              hipStream_t stream)
{
    (void)out_size; (void)ws_size;

    int wb = 2;
    for (int i = 1; i < n_in; ++i) { if (in_sizes[i] == 6912) { wb = i; break; } }

    const void* x = d_in[0];
    const void *w0a=d_in[wb+0],  *s0a=d_in[wb+1],  *b0a=d_in[wb+2];
    const void *w0b=d_in[wb+3],  *s0b=d_in[wb+4],  *b0b=d_in[wb+5];
    const void *wd0=d_in[wb+6],  *sd0=d_in[wb+7],  *bd0=d_in[wb+8];
    const void *w1a=d_in[wb+9],  *s1a=d_in[wb+10], *b1a=d_in[wb+11];
    const void *w1b=d_in[wb+12], *s1b=d_in[wb+13], *b1b=d_in[wb+14];
    const void *wd1=d_in[wb+15], *sd1=d_in[wb+16], *bd1=d_in[wb+17];
    const void *w2a=d_in[wb+18], *s2a=d_in[wb+19], *b2a=d_in[wb+20];
    const void *w2b=d_in[wb+21], *s2b=d_in[wb+22], *b2b=d_in[wb+23];
    const void *w2c=d_in[wb+24], *s2c=d_in[wb+25], *b2c=d_in[wb+26];

    // ---- workspace layout (~128 MiB of 512) ----
    char* ws = (char*)d_ws;
    int*   idxmap = (int*)(ws);                     //  8,388,608
    u16*   Fb0    = (u16*)(ws + 8388608);           //  4,194,304
    u16*   Fb1    = (u16*)(ws + 12582912);          //  4,194,304
    u16*   Fb2    = (u16*)(ws + 16777216);          //  4,194,304
    u16*   Rb1    = (u16*)(ws + 25165824);          // 16,777,216
    u16*   Rb2    = (u16*)(ws + 41943040);          // 16,777,216
    u8*    m1     = (u8*)(ws + 58720256);           //    262,144
    u8*    m2     = (u8*)(ws + 58982400);           //     32,768
    u32*   cnt    = (u32*)(ws + 59015168);          //        256
    int*   alist  = (int*)(ws + 59015424);          //    524,288
    u16*   FR     = (u16*)(ws + 59539712);          //    943,616
    float* S      = (float*)(ws + 60483328);        //      3,072
    u32*   flag   = (u32*)(ws + 60486400);          //        256
    u64*   bmask  = (u64*)(ws + 60486656);          //    262,144
    u32*   bcnt   = (u32*)(ws + 60748800);          //     32,768
    u32*   boff   = (u32*)(ws + 60781568);          //     32,768
    u16*   Xp     = (u16*)(ws + 67108864);          // 67,108,864 (block-packed features)

    u16* wfs0a = FR + 0;
    u16* wfs0b = FR + 7168;
    u16* fd0   = FR + 14336;
    u16* f1a   = FR + 28672;
    u16* f1b   = FR + 56320;
    u16* fd1   = FR + 83968;
    u16* f2a   = FR + 139264;
    u16* f2b   = FR + 249856;
    u16* f2c   = FR + 360448;

    PAll J;
    const void* jsrc[9] = {w0a, w0b, wd0, w1a, w1b, wd1, w2a, w2b, w2c};
    const u32 jlen[9]   = {7168,7168,14336,27648,27648,55296,110592,110592,110592};
    const int jcin[9]   = {16,16,16,32,32,32,64,64,64};
    const int jcout[9]  = {16,16,32,32,32,64,64,64,64};
    const int jmode[9]  = {2,2,1,0,0,0,0,0,0};
    u32 acc = 0;
    for (int i = 0; i < 9; ++i){
        J.w[i] = jsrc[i]; J.wstart[i] = acc; acc += jlen[i];
        J.cin[i] = jcin[i]; J.cout[i] = jcout[i]; J.mode[i] = jmode[i];
    }
    J.wstart[9] = acc;
    const void* sv[18] = {s0a,b0a,s0b,b0b,sd0,bd0,s1a,b1a,s1b,b1b,sd1,bd1,s2a,b2a,s2b,b2b,s2c,b2c};
    for (int i = 0; i < 18; ++i) J.s[i] = sv[i];
    const u32 ptot = acc + 768;
    const int prep_blocks = (int)((ptot + 255) / 256);

    float *cs0a=S+0,  *cb0a=S+16,  *cs0b=S+32,  *cb0b=S+48;
    float *csd0=S+64, *cbd0=S+96,  *cs1a=S+128, *cb1a=S+160, *cs1b=S+192, *cb1b=S+224;
    float *csd1=S+256,*cbd1=S+320, *cs2a=S+384, *cb2a=S+448, *cs2b=S+512, *cb2b=S+576, *cs2c=S+640, *cb2c=S+704;

    // fused prep + actmask (12 launches total)
    prepact_k<<<8192 + prep_blocks, 256, 0, stream>>>(J, FR, S, (const u16*)s0a, flag,
                                                      x, bmask, bcnt, Xp);
    aux_k<<<257, 1024, 0, stream>>>(bcnt, boff, cnt, bmask, m1);
    scatter2m_k<<<8320, 256, 0, stream>>>(Xp, bmask, boff, idxmap, alist, Fb0, m1, m2);

    // stage A (128^3, 16ch, ~5% active) — M=32 slots/wave
    sconvm_k<<<1024, 256, 0, stream>>>(Fb0, idxmap, alist, cnt, wfs0a, cs0a, cb0a, Fb1);
    sconvm_k<<<1024, 256, 0, stream>>>(Fb1, idxmap, alist, cnt, wfs0b, cs0b, cb0b, Fb2);
    // down0 -> 64^3 x 32 bf16 NDHWC — M=32 voxels/wave
    convd0m_k<<<2048, 256, 0, stream>>>(Fb2, idxmap, fd0, csd0, cbd0, m1, Rb1);
    // 64^3 stage — M=32/wave, 2x2-row LDS-staged (512-thread blocks, 64 KB LDS)
    mconvw_k<64,32,32,false><<<1024, 512, 0, stream>>>(Rb1, f1a, cs1a, cb1a, m1, Rb2, flag);
    mconvw_k<64,32,32,false><<<1024, 512, 0, stream>>>(Rb2, f1b, cs1b, cb1b, m1, Rb1, flag);
    // down1 -> 32^3 x 64 (stride 2, direct-global path)
    mconv_k<64,32,32,64,2,false><<<512, 256, 0, stream>>>(Rb1, fd1, csd1, cbd1, m2, Rb2, flag);
    // 32^3 stage — M=32/wave (256-thread blocks)
    mconvw_k<32,64,64,false><<<256, 256, 0, stream>>>(Rb2, f2a, cs2a, cb2a, m2, Rb1, flag);
    mconvw_k<32,64,64,false><<<256, 256, 0, stream>>>(Rb1, f2b, cs2b, cb2b, m2, Rb2, flag);
    // final conv: NCDHW f32 (or bf16 per flag) to d_out
    mconvw_k<32,64,64,true ><<<256, 256, 0, stream>>>(Rb2, f2c, cs2c, cb2c, m2, d_out, flag);
}

// Round 18
// 479.906 us; speedup vs baseline: 1.0164x; 1.0164x over previous
//
#include <hip/hip_runtime.h>
#include <cstdint>

typedef unsigned short u16;
typedef unsigned int u32;
typedef unsigned char u8;
typedef unsigned long long u64;
typedef __attribute__((ext_vector_type(8))) short short8;
typedef __attribute__((ext_vector_type(4))) float f32x4;

#define CAP 131072  // max compact slots at 128^3 (~105k expected active)

__device__ __forceinline__ float bf1(u16 v){ union{u32 i; float f;} c; c.i = ((u32)v) << 16; return c.f; }
__device__ __forceinline__ u16 f2bf(float f){
    union{float f; u32 i;} c; c.f = f; u32 i = c.i;
    return (u16)((i + 0x7FFFu + ((i >> 16) & 1u)) >> 16);   // RTNE
}
__device__ __forceinline__ u16 bits2bf(u32 b){ union{u32 i; float f;} c; c.i = b; return f2bf(c.f); }

constexpr int ilog2c(int n){ return n <= 1 ? 0 : 1 + ilog2c(n / 2); }

struct PAll {
    const void* w[9];
    u32 wstart[10];
    int cin[9], cout[9], mode[9];   // 0=16x16 wfrag, 1=d0 pair(16->32), 2=subm0 pair(16->16)
    const void* s[18];
};

// ---- fused phase 0+1: blocks [0,8192) = active bitmask + packed features;
// blocks [8192,..) = weight-fragment + scale prep. Flag self-derived per thread. ----
__global__ __launch_bounds__(256)
void prepact_k(PAll J, u16* __restrict__ FR, float* __restrict__ S,
               const u16* __restrict__ s0a_probe, u32* __restrict__ flag,
               const void* __restrict__ xv, u64* __restrict__ bmask,
               u32* __restrict__ bcnt, u16* __restrict__ Xp){
    int ok = 1;
    #pragma unroll
    for (int i = 0; i < 8; i += 2){
        u16 vv = s0a_probe[i];
        if (vv < 0x3F00u || vv > 0x3FC0u) ok = 0;
    }
    const u32 isbf = ok ? 1u : 0u;

    if (blockIdx.x < 8192){
        const int v = blockIdx.x * 256 + threadIdx.x;
        const size_t N = 2097152;
        u16 vals[16];
        u32 a = 0;
        if (isbf) {
            const u16* x = (const u16*)xv;
            #pragma unroll
            for (int c = 0; c < 16; ++c){
                const u16 b = x[(size_t)c * N + v];
                vals[c] = b;
                a |= (u32)b & 0x7FFFu;
            }
        } else {
            const u32* x = (const u32*)xv;
            #pragma unroll
            for (int c = 0; c < 16; ++c){
                const u32 b = x[(size_t)c * N + v];
                vals[c] = bits2bf(b);
                a |= b & 0x7FFFFFFFu;
            }
        }
        const bool act = (a != 0);
        const u64 m = __ballot(act);
        __shared__ u32 wc[4];
        const int lane = threadIdx.x & 63, wv = threadIdx.x >> 6;
        if (lane == 0) { bmask[v >> 6] = m; wc[wv] = (u32)__popcll(m); }
        __syncthreads();
        if (threadIdx.x == 0) bcnt[blockIdx.x] = wc[0] + wc[1] + wc[2] + wc[3];
        if (act){
            u32 wbase = 0;
            for (int i = 0; i < wv; ++i) wbase += wc[i];
            const u32 local = wbase + (u32)__popcll(m & ((1ull << lane) - 1ull));
            u16* dst = Xp + ((size_t)blockIdx.x * 256 + local) * 16;
            *(short8*)(dst)     = *(const short8*)(vals);
            *(short8*)(dst + 8) = *(const short8*)(vals + 8);
        }
        return;
    }

    const int gi = (int)(blockIdx.x - 8192) * 256 + threadIdx.x;
    if (gi == 0) flag[0] = isbf;

    const int wtot = (int)J.wstart[9];
    if (gi < wtot){
        int j = 0;
        while (gi >= (int)J.wstart[j + 1]) ++j;
        const int i = gi - (int)J.wstart[j];
        const void* w = J.w[j];
        const int CIN = J.cin[j], COUT = J.cout[j];
        const int jj = i & 7;
        const int lane = (i >> 3) & 63;
        int rest = i >> 9;
        int src = -1;
        if (J.mode[j] == 0){
            const int KC = CIN >> 5, NT = COUT >> 4;
            const int nt = rest % NT; rest /= NT;
            const int kc = rest % KC; const int tap = rest / KC;
            const int k = kc * 32 + (lane >> 4) * 8 + jj;
            const int co = nt * 16 + (lane & 15);
            src = (tap * CIN + k) * COUT + co;
        } else if (J.mode[j] == 1){
            const int nt = rest & 1; const int pair = rest >> 1;
            const int kg = (lane >> 4) * 8 + jj;
            const int tap = pair * 2 + (kg >> 4);
            const int ci = kg & 15;
            const int co = nt * 16 + (lane & 15);
            if (tap < 27) src = (tap * 16 + ci) * 32 + co;
        } else {
            const int pair = rest;
            const int kg = (lane >> 4) * 8 + jj;
            const int tap = pair * 2 + (kg >> 4);
            const int ci = kg & 15;
            const int co = lane & 15;
            if (tap < 27) src = (tap * 16 + ci) * 16 + co;
        }
        float v = 0.f;
        if (src >= 0) v = isbf ? bf1(((const u16*)w)[src]) : ((const float*)w)[src];
        FR[gi] = f2bf(v);
    } else {
        const int i2 = gi - wtot;
        const int len[18] = {16,16,16,16,32,32,32,32,32,32,64,64,64,64,64,64,64,64};
        const int off[18] = {0,16,32,48,64,96,128,160,192,224,256,320,384,448,512,576,640,704};
        if (i2 < 768){
            int b = 0, base = 0;
            while (i2 >= base + len[b]) { base += len[b]; ++b; }
            const int t = i2 - base;
            const float v = isbf ? bf1(((const u16*)J.s[b])[t]) : ((const float*)J.s[b])[t];
            S[off[b] + t] = v;
        }
    }
}

// ---- fused aux: block 0 = exclusive scan; blocks 1..256 = m1 from bmask ----
__global__ __launch_bounds__(1024)
void aux_k(const u32* __restrict__ bcnt, u32* __restrict__ boff, u32* __restrict__ cnt,
           const u64* __restrict__ bmask, u8* __restrict__ m1){
    if (blockIdx.x == 0){
        __shared__ u32 lds[1024];
        const int t = threadIdx.x;
        u32 loc[8]; u32 s = 0;
        #pragma unroll
        for (int i = 0; i < 8; ++i){ loc[i] = s; s += bcnt[t * 8 + i]; }
        lds[t] = s;
        __syncthreads();
        u32 v = s;
        for (int d = 1; d < 1024; d <<= 1){
            u32 o = (t >= d) ? lds[t - d] : 0;
            __syncthreads();
            v += o; lds[t] = v;
            __syncthreads();
        }
        const u32 base = v - s;
        #pragma unroll
        for (int i = 0; i < 8; ++i) boff[t * 8 + i] = base + loc[i];
        if (t == 1023) cnt[0] = v;
    } else {
        const int v = (blockIdx.x - 1) * 1024 + threadIdx.x;
        const int xo = v & 63, yo = (v >> 6) & 63, zo = v >> 12;
        u32 a = 0;
        #pragma unroll
        for (int kz = 0; kz < 3; ++kz){ const int iz = 2*zo + kz - 1; if ((unsigned)iz >= 128u) continue;
          #pragma unroll
          for (int ky = 0; ky < 3; ++ky){ const int iy = 2*yo + ky - 1; if ((unsigned)iy >= 128u) continue;
            #pragma unroll
            for (int kx = 0; kx < 3; ++kx){ const int ix = 2*xo + kx - 1; if ((unsigned)ix >= 128u) continue;
              const int vv = (iz * 128 + iy) * 128 + ix;
              a |= (u32)((bmask[vv >> 6] >> (vv & 63)) & 1ull);
        }}}
        m1[v] = (u8)a;
    }
}

// ---- fused: scatter (Xp -> Fb0) + m1->m2 downsample ----
__global__ __launch_bounds__(256)
void scatter2m_k(const u16* __restrict__ Xp, const u64* __restrict__ bmask,
                 const u32* __restrict__ boff, int* __restrict__ idxmap,
                 int* __restrict__ alist, u16* __restrict__ f,
                 const u8* __restrict__ m1, u8* __restrict__ m2){
    if (blockIdx.x < 8192){
        const int v = blockIdx.x * 256 + threadIdx.x;
        const int lane = threadIdx.x & 63, wv = threadIdx.x >> 6;
        const u64 m = bmask[v >> 6];
        __shared__ u32 wc[4];
        if (lane == 0) wc[wv] = (u32)__popcll(m);
        __syncthreads();
        u32 wbase = 0;
        for (int i = 0; i < wv; ++i) wbase += wc[i];
        const bool act = (m >> lane) & 1ull;
        const u32 rank = (u32)__popcll(m & ((1ull << lane) - 1ull));
        int slot = -1;
        if (act){
            const u32 sl = boff[blockIdx.x] + wbase + rank;
            if (sl < CAP){
                slot = (int)sl;
                alist[slot] = v;
                const u16* src = Xp + ((size_t)blockIdx.x * 256 + wbase + rank) * 16;
                u16* dst = f + (size_t)slot * 16;
                *(short8*)(dst)     = *(const short8*)(src);
                *(short8*)(dst + 8) = *(const short8*)(src + 8);
            }
        }
        idxmap[v] = slot;
    } else {
        const int v = (int)(blockIdx.x - 8192) * 256 + threadIdx.x;
        const int xo = v & 31, yo = (v >> 5) & 31, zo = v >> 10;
        u8 a = 0;
        #pragma unroll
        for (int kz = 0; kz < 3; ++kz){ const int iz = 2*zo + kz - 1; if ((unsigned)iz >= 64u) continue;
          #pragma unroll
          for (int ky = 0; ky < 3; ++ky){ const int iy = 2*yo + ky - 1; if ((unsigned)iy >= 64u) continue;
            #pragma unroll
            for (int kx = 0; kx < 3; ++kx){ const int ix = 2*xo + kx - 1; if ((unsigned)ix >= 64u) continue;
              a |= m1[((size_t)iz * 64 + iy) * 64 + ix];
        }}}
        m2[v] = a;
    }
}

// ---- MFMA sparse subm conv at 128^3: compact bf16 16ch -> 16ch ----
__global__ __launch_bounds__(256)
void sconvm_k(const u16* __restrict__ fin, const int* __restrict__ idxmap,
              const int* __restrict__ alist, const u32* __restrict__ cnt,
              const u16* __restrict__ wf, const float* __restrict__ sc,
              const float* __restrict__ sh, u16* __restrict__ fout){
    const int n = min((int)cnt[0], CAP);
    const int j = blockIdx.x * 4 + (threadIdx.x >> 6);
    const int sbase = j * 16;
    if (sbase >= n) return;
    const int lane = threadIdx.x & 63;
    const int m = lane & 15, quad = lane >> 4;

    const int s = sbase + m;
    const int v = (s < n) ? alist[s] : -1;
    int xo = 0, yo = 0, zo = 0;
    if (v >= 0){ xo = v & 127; yo = (v >> 7) & 127; zo = v >> 14; }

    f32x4 acc = {0.f,0.f,0.f,0.f};
    #pragma unroll
    for (int p = 0; p < 14; ++p){
        const int tp = p * 2 + (quad >> 1);
        short8 a = {0,0,0,0,0,0,0,0};
        if (v >= 0 && tp < 27){
            const int kz = tp / 9, ky = (tp / 3) % 3, kx = tp % 3;
            const int iz = zo + kz - 1, iy = yo + ky - 1, ix = xo + kx - 1;
            if ((unsigned)iz < 128u && (unsigned)iy < 128u && (unsigned)ix < 128u){
                const int sn = idxmap[((size_t)iz * 128 + iy) * 128 + ix];
                if (sn >= 0) a = *(const short8*)(fin + (size_t)sn * 16 + (quad & 1) * 8);
            }
        }
        short8 b = *(const short8*)(wf + ((size_t)p * 64 + lane) * 8);
        acc = __builtin_amdgcn_mfma_f32_16x16x32_bf16(a, b, acc, 0, 0, 0);
    }

    const int co = lane & 15;
    const float scl = sc[co], shf = sh[co];
    #pragma unroll
    for (int r = 0; r < 4; ++r){
        const int srow = sbase + quad * 4 + r;
        if (srow < n){
            fout[(size_t)srow * 16 + co] = f2bf(fmaxf(acc[r] * scl + shf, 0.f));
        }
    }
}

// ---- down0 MFMA: compact bf16 16ch @128^3 -> bf16 NDHWC 32ch @64^3 ----
__global__ __launch_bounds__(256)
void convd0m_k(const u16* __restrict__ fbuf, const int* __restrict__ idxmap,
               const u16* __restrict__ wf, const float* __restrict__ sc,
               const float* __restrict__ sh, const u8* __restrict__ mk,
               u16* __restrict__ out)
{
    const int wj = blockIdx.x * 4 + (threadIdx.x >> 6);
    const int lane = threadIdx.x & 63;
    const int m = lane & 15, quad = lane >> 4;
    const int xo_b = (wj & 3) * 16;
    const int yo = (wj >> 2) & 63;
    const int zo = wj >> 8;

    f32x4 acc0 = {0.f,0.f,0.f,0.f}, acc1 = {0.f,0.f,0.f,0.f};
    const int ix_m = (xo_b + m) * 2 - 1;

    #pragma unroll
    for (int p = 0; p < 14; ++p){
        const int tp = p * 2 + (quad >> 1);
        short8 a = {0,0,0,0,0,0,0,0};
        if (tp < 27){
            const int kz = tp / 9, ky = (tp / 3) % 3, kx = tp % 3;
            const int iz = 2*zo + kz - 1, iy = 2*yo + ky - 1, ix = ix_m + kx;
            if ((unsigned)iz < 128u && (unsigned)iy < 128u && (unsigned)ix < 128u){
                const int sn = idxmap[((size_t)iz * 128 + iy) * 128 + ix];
                if (sn >= 0) a = *(const short8*)(fbuf + (size_t)sn * 16 + (quad & 1) * 8);
            }
        }
        short8 b0 = *(const short8*)(wf + ((size_t)(p*2+0) * 64 + lane) * 8);
        short8 b1 = *(const short8*)(wf + ((size_t)(p*2+1) * 64 + lane) * 8);
        acc0 = __builtin_amdgcn_mfma_f32_16x16x32_bf16(a, b0, acc0, 0, 0, 0);
        acc1 = __builtin_amdgcn_mfma_f32_16x16x32_bf16(a, b1, acc1, 0, 0, 0);
    }

    const int vb = wj * 16 + quad * 4;
    const u32 m4 = *(const u32*)(mk + vb);
    const int n = lane & 15;
    #pragma unroll
    for (int nt = 0; nt < 2; ++nt){
        const int co = nt * 16 + n;
        const float s = sc[co], h = sh[co];
        const f32x4 acc = nt ? acc1 : acc0;
        #pragma unroll
        for (int r = 0; r < 4; ++r){
            float val = fmaxf(acc[r] * s + h, 0.f);
            val = ((m4 >> (8*r)) & 0xFFu) ? val : 0.f;
            out[(size_t)(vb + r) * 32 + co] = f2bf(val);
        }
    }
}

// ---- generic direct-global MFMA conv; retained for down1 (stride 2) only ----
template<int DIN, int DOUT, int CIN, int COUT, int STRIDE, bool FINAL>
__global__ __launch_bounds__(256)
void mconv_k(const u16* __restrict__ in, const u16* __restrict__ wf,
             const float* __restrict__ sc, const float* __restrict__ sh,
             const u8* __restrict__ mk, void* __restrict__ out,
             const u32* __restrict__ flag)
{
    constexpr int KC = CIN / 32;
    constexpr int NT = COUT / 16;
    constexpr int XT = DOUT / 16;
    const int wj = blockIdx.x * 4 + (threadIdx.x >> 6);
    const int lane = threadIdx.x & 63;
    const int m = lane & 15, quad = lane >> 4;

    const int xo_b = (wj % XT) * 16;
    const int yo = (wj / XT) % DOUT;
    const int zo = wj / (XT * DOUT);

    f32x4 acc[NT];
    #pragma unroll
    for (int i = 0; i < NT; ++i) acc[i] = (f32x4){0.f,0.f,0.f,0.f};

    const int ix0 = (xo_b + m) * STRIDE - 1;
    for (int kz = 0; kz < 3; ++kz){
      const int iz = zo * STRIDE + kz - 1;
      if ((unsigned)iz >= (unsigned)DIN) continue;
      for (int ky = 0; ky < 3; ++ky){
        const int iy = yo * STRIDE + ky - 1;
        if ((unsigned)iy >= (unsigned)DIN) continue;
        const size_t rowb = ((size_t)iz * DIN + iy) * DIN;
        #pragma unroll
        for (int kx = 0; kx < 3; ++kx){
          const int ix = ix0 + kx;
          const bool v = (unsigned)ix < (unsigned)DIN;
          const int tap = (kz*3 + ky)*3 + kx;
          const u16* ap = in + (rowb + ix) * CIN + quad * 8;
          const u16* bp = wf + (size_t)tap * KC * NT * 512 + lane * 8;
          #pragma unroll
          for (int kc = 0; kc < KC; ++kc){
            short8 a = {0,0,0,0,0,0,0,0};
            if (v) a = *(const short8*)(ap + kc * 32);
            #pragma unroll
            for (int nt = 0; nt < NT; ++nt){
              short8 b = *(const short8*)(bp + (kc * NT + nt) * 512);
              acc[nt] = __builtin_amdgcn_mfma_f32_16x16x32_bf16(a, b, acc[nt], 0, 0, 0);
            }
          }
    }}}

    const int vb = wj * 16 + quad * 4;
    const u32 m4 = *(const u32*)(mk + vb);
    const int n = lane & 15;
    #pragma unroll
    for (int nt = 0; nt < NT; ++nt){
        const int co = nt * 16 + n;
        const float s = sc[co], h = sh[co];
        #pragma unroll
        for (int r = 0; r < 4; ++r){
            float val = fmaxf(acc[nt][r] * s + h, 0.f);
            val = ((m4 >> (8*r)) & 0xFFu) ? val : 0.f;
            ((u16*)out)[(size_t)(vb + r) * COUT + co] = f2bf(val);
        }
    }
    (void)flag;
}

// ---- LDS-staged 16x16 MFMA conv, stride 1, 2x2 output rows per block, M=32/wave ----
template<int D, int CIN, int COUT, bool FINAL>
__global__ __launch_bounds__((D/32)*4*64)
void mconvw_k(const u16* __restrict__ in, const u16* __restrict__ wf,
              const float* __restrict__ sc, const float* __restrict__ sh,
              const u8* __restrict__ mk, void* __restrict__ out,
              const u32* __restrict__ flag)
{
    constexpr int KC = CIN / 32;
    constexpr int NT = COUT / 16;
    constexpr int CH8 = CIN / 8;
    constexpr int WPR = D / 32;
    constexpr int BT = WPR * 4 * 64;
    __shared__ u16 tile[16 * 2048];

    const int t = threadIdx.x;
    const int yp = blockIdx.x % (D / 2);
    const int zp = blockIdx.x / (D / 2);

    #pragma unroll
    for (int ri = 0; ri < 16; ++ri){
        const int dz = ri >> 2, jy = ri & 3;
        const int iz = 2*zp + dz - 1, iy = 2*yp + jy - 1;
        if ((unsigned)iz < (unsigned)D && (unsigned)iy < (unsigned)D){
            const u16* src = in + ((size_t)(iz * D + iy) * D) * CIN;
            u16* dst = &tile[ri * 2048];
            for (int c = t; c < D * CH8; c += BT){
                const int x = c / CH8, c8 = c % CH8;
                *(short8*)(dst + (c8 * D + x) * 8) = *(const short8*)(src + c * 8);
            }
        }
    }
    __syncthreads();

    const int lane = t & 63, w = t >> 6;
    const int r = w / WPR;
    const int r2z = r >> 1, r2y = r & 1;
    const int xo_b = (w % WPR) * 32;
    const int zo = 2*zp + r2z, yo = 2*yp + r2y;
    const int m = lane & 15, quad = lane >> 4;

    f32x4 acc0[NT], acc1[NT];
    #pragma unroll
    for (int i = 0; i < NT; ++i){ acc0[i] = (f32x4){0.f,0.f,0.f,0.f}; acc1[i] = (f32x4){0.f,0.f,0.f,0.f}; }

    #pragma unroll
    for (int kz = 0; kz < 3; ++kz){
      const int iz = zo + kz - 1;
      if ((unsigned)iz >= (unsigned)D) continue;
      #pragma unroll
      for (int ky = 0; ky < 3; ++ky){
        const int iy = yo + ky - 1;
        if ((unsigned)iy >= (unsigned)D) continue;
        const u16* row = &tile[((r2z + kz) * 4 + (r2y + ky)) * 2048];
        #pragma unroll
        for (int kx = 0; kx < 3; ++kx){
          const int ix0 = xo_b + m + kx - 1;
          const int ix1 = ix0 + 16;
          const bool aok0 = (unsigned)ix0 < (unsigned)D;
          const bool aok1 = (unsigned)ix1 < (unsigned)D;
          const int tap = (kz * 3 + ky) * 3 + kx;
          const u16* bp = wf + (size_t)tap * KC * NT * 512 + lane * 8;
          #pragma unroll
          for (int kc = 0; kc < KC; ++kc){
            short8 a0 = {0,0,0,0,0,0,0,0};
            short8 a1 = {0,0,0,0,0,0,0,0};
            if (aok0) a0 = *(const short8*)(row + ((kc * 4 + quad) * D + ix0) * 8);
            if (aok1) a1 = *(const short8*)(row + ((kc * 4 + quad) * D + ix1) * 8);
            #pragma unroll
            for (int nt = 0; nt < NT; ++nt){
              short8 b = *(const short8*)(bp + (kc * NT + nt) * 512);
              acc0[nt] = __builtin_amdgcn_mfma_f32_16x16x32_bf16(a0, b, acc0[nt], 0, 0, 0);
              acc1[nt] = __builtin_amdgcn_mfma_f32_16x16x32_bf16(a1, b, acc1[nt], 0, 0, 0);
            }
          }
        }
      }
    }

    const int base = (zo * D + yo) * D;
    const int vb0 = base + xo_b + quad * 4;
    const int vb1 = vb0 + 16;
    const u32 m4_0 = *(const u32*)(mk + vb0);
    const u32 m4_1 = *(const u32*)(mk + vb1);
    const int n = lane & 15;
    if (FINAL) {
        const bool bfout = flag[0] != 0;
        #pragma unroll
        for (int nt = 0; nt < NT; ++nt){
            const int co = nt * 16 + n;
            const float s = sc[co], h = sh[co];
            float4 o0, o1;
            float* p0 = &o0.x; float* p1 = &o1.x;
            #pragma unroll
            for (int r4 = 0; r4 < 4; ++r4){
                float v0 = fmaxf(acc0[nt][r4] * s + h, 0.f);
                float v1 = fmaxf(acc1[nt][r4] * s + h, 0.f);
                p0[r4] = ((m4_0 >> (8*r4)) & 0xFFu) ? v0 : 0.f;
                p1[r4] = ((m4_1 >> (8*r4)) & 0xFFu) ? v1 : 0.f;
            }
            if (!bfout) {
                *(float4*)((float*)out + (size_t)co * (D*D*D) + vb0) = o0;
                *(float4*)((float*)out + (size_t)co * (D*D*D) + vb1) = o1;
            } else {
                u16* ob0 = (u16*)out + (size_t)co * (D*D*D) + vb0;
                u16* ob1 = (u16*)out + (size_t)co * (D*D*D) + vb1;
                #pragma unroll
                for (int r4 = 0; r4 < 4; ++r4){ ob0[r4] = f2bf(p0[r4]); ob1[r4] = f2bf(p1[r4]); }
            }
        }
    } else {
        #pragma unroll
        for (int nt = 0; nt < NT; ++nt){
            const int co = nt * 16 + n;
            const float s = sc[co], h = sh[co];
            #pragma unroll
            for (int r4 = 0; r4 < 4; ++r4){
                float v0 = fmaxf(acc0[nt][r4] * s + h, 0.f);
                float v1 = fmaxf(acc1[nt][r4] * s + h, 0.f);
                v0 = ((m4_0 >> (8*r4)) & 0xFFu) ? v0 : 0.f;
                v1 = ((m4_1 >> (8*r4)) & 0xFFu) ? v1 : 0.f;
                ((u16*)out)[(size_t)(vb0 + r4) * COUT + co] = f2bf(v0);
                ((u16*)out)[(size_t)(vb1 + r4) * COUT + co] = f2bf(v1);
            }
        }
    }
}

extern "C" void kernel_launch(void* const* d_in, const int* in_sizes, int n_in,
                              void* d_out, int out_size, void* d_ws, size_t ws_size,
                              hipStream_t stream)
{
    (void)out_size; (void)ws_size;

    int wb = 2;
    for (int i = 1; i < n_in; ++i) { if (in_sizes[i] == 6912) { wb = i; break; } }

    const void* x = d_in[0];
    const void *w0a=d_in[wb+0],  *s0a=d_in[wb+1],  *b0a=d_in[wb+2];
    const void *w0b=d_in[wb+3],  *s0b=d_in[wb+4],  *b0b=d_in[wb+5];
    const void *wd0=d_in[wb+6],  *sd0=d_in[wb+7],  *bd0=d_in[wb+8];
    const void *w1a=d_in[wb+9],  *s1a=d_in[wb+10], *b1a=d_in[wb+11];
    const void *w1b=d_in[wb+12], *s1b=d_in[wb+13], *b1b=d_in[wb+14];
    const void *wd1=d_in[wb+15], *sd1=d_in[wb+16], *bd1=d_in[wb+17];
    const void *w2a=d_in[wb+18], *s2a=d_in[wb+19], *b2a=d_in[wb+20];
    const void *w2b=d_in[wb+21], *s2b=d_in[wb+22], *b2b=d_in[wb+23];
    const void *w2c=d_in[wb+24], *s2c=d_in[wb+25], *b2c=d_in[wb+26];

    // ---- workspace layout (~128 MiB of 512) ----
    char* ws = (char*)d_ws;
    int*   idxmap = (int*)(ws);                     //  8,388,608
    u16*   Fb0    = (u16*)(ws + 8388608);           //  4,194,304
    u16*   Fb1    = (u16*)(ws + 12582912);          //  4,194,304
    u16*   Fb2    = (u16*)(ws + 16777216);          //  4,194,304
    u16*   Rb1    = (u16*)(ws + 25165824);          // 16,777,216
    u16*   Rb2    = (u16*)(ws + 41943040);          // 16,777,216
    u8*    m1     = (u8*)(ws + 58720256);           //    262,144
    u8*    m2     = (u8*)(ws + 58982400);           //     32,768
    u32*   cnt    = (u32*)(ws + 59015168);          //        256
    int*   alist  = (int*)(ws + 59015424);          //    524,288
    u16*   FR     = (u16*)(ws + 59539712);          //    943,616
    float* S      = (float*)(ws + 60483328);        //      3,072
    u32*   flag   = (u32*)(ws + 60486400);          //        256
    u64*   bmask  = (u64*)(ws + 60486656);          //    262,144
    u32*   bcnt   = (u32*)(ws + 60748800);          //     32,768
    u32*   boff   = (u32*)(ws + 60781568);          //     32,768
    u16*   Xp     = (u16*)(ws + 67108864);          // 67,108,864 (block-packed features)

    u16* wfs0a = FR + 0;
    u16* wfs0b = FR + 7168;
    u16* fd0   = FR + 14336;
    u16* f1a   = FR + 28672;
    u16* f1b   = FR + 56320;
    u16* fd1   = FR + 83968;
    u16* f2a   = FR + 139264;
    u16* f2b   = FR + 249856;
    u16* f2c   = FR + 360448;

    PAll J;
    const void* jsrc[9] = {w0a, w0b, wd0, w1a, w1b, wd1, w2a, w2b, w2c};
    const u32 jlen[9]   = {7168,7168,14336,27648,27648,55296,110592,110592,110592};
    const int jcin[9]   = {16,16,16,32,32,32,64,64,64};
    const int jcout[9]  = {16,16,32,32,32,64,64,64,64};
    const int jmode[9]  = {2,2,1,0,0,0,0,0,0};
    u32 acc = 0;
    for (int i = 0; i < 9; ++i){
        J.w[i] = jsrc[i]; J.wstart[i] = acc; acc += jlen[i];
        J.cin[i] = jcin[i]; J.cout[i] = jcout[i]; J.mode[i] = jmode[i];
    }
    J.wstart[9] = acc;
    const void* sv[18] = {s0a,b0a,s0b,b0b,sd0,bd0,s1a,b1a,s1b,b1b,sd1,bd1,s2a,b2a,s2b,b2b,s2c,b2c};
    for (int i = 0; i < 18; ++i) J.s[i] = sv[i];
    const u32 ptot = acc + 768;
    const int prep_blocks = (int)((ptot + 255) / 256);

    float *cs0a=S+0,  *cb0a=S+16,  *cs0b=S+32,  *cb0b=S+48;
    float *csd0=S+64, *cbd0=S+96,  *cs1a=S+128, *cb1a=S+160, *cs1b=S+192, *cb1b=S+224;
    float *csd1=S+256,*cbd1=S+320, *cs2a=S+384, *cb2a=S+448, *cs2b=S+512, *cb2b=S+576, *cs2c=S+640, *cb2c=S+704;

    // fused prep + actmask (12 launches total)
    prepact_k<<<8192 + prep_blocks, 256, 0, stream>>>(J, FR, S, (const u16*)s0a, flag,
                                                      x, bmask, bcnt, Xp);
    aux_k<<<257, 1024, 0, stream>>>(bcnt, boff, cnt, bmask, m1);
    scatter2m_k<<<8320, 256, 0, stream>>>(Xp, bmask, boff, idxmap, alist, Fb0, m1, m2);

    // stage A (128^3, 16ch, ~5% active)
    sconvm_k<<<2048, 256, 0, stream>>>(Fb0, idxmap, alist, cnt, wfs0a, cs0a, cb0a, Fb1);
    sconvm_k<<<2048, 256, 0, stream>>>(Fb1, idxmap, alist, cnt, wfs0b, cs0b, cb0b, Fb2);
    // down0 -> 64^3 x 32 bf16 NDHWC
    convd0m_k<<<4096, 256, 0, stream>>>(Fb2, idxmap, fd0, csd0, cbd0, m1, Rb1);
    // 64^3 stage — M=32/wave, 2x2-row LDS-staged (512-thread blocks, 64 KB LDS)
    mconvw_k<64,32,32,false><<<1024, 512, 0, stream>>>(Rb1, f1a, cs1a, cb1a, m1, Rb2, flag);
    mconvw_k<64,32,32,false><<<1024, 512, 0, stream>>>(Rb2, f1b, cs1b, cb1b, m1, Rb1, flag);
    // down1 -> 32^3 x 64 (stride 2, direct-global path)
    mconv_k<64,32,32,64,2,false><<<512, 256, 0, stream>>>(Rb1, fd1, csd1, cbd1, m2, Rb2, flag);
    // 32^3 stage — M=32/wave (256-thread blocks)
    mconvw_k<32,64,64,false><<<256, 256, 0, stream>>>(Rb2, f2a, cs2a, cb2a, m2, Rb1, flag);
    mconvw_k<32,64,64,false><<<256, 256, 0, stream>>>(Rb1, f2b, cs2b, cb2b, m2, Rb2, flag);
    // final conv: NCDHW f32 (or bf16 per flag) to d_out
    mconvw_k<32,64,64,true ><<<256, 256, 0, stream>>>(Rb2, f2c, cs2c, cb2c, m2, d_out, flag);
}